// Round 2
// baseline (426.428 us; speedup 1.0000x reference)
//
#include <hip/hip_runtime.h>
#include <stdint.h>

// Problem: B=4, S=2048, D_IN=1024, H=1024; fp32 in/out.
// Pipeline: [prep_mask] [split qkv->bf16 hi/lo] [split+transpose W (LDS tile)]
//           [proj_qk 256^2 8-phase split-GEMM -> Qhi/Qlo/Khi/Klo]
//           [proj_v GEMM plain bf16 -> Vt]
//           [scores 256^2 8-phase split-GEMM *32 + maskbias -> fp32 scores]
//           [softmax per-wave in-place -> bf16 P]   [PV GEMM bf16 -> out]
// R10: 256^2 8-phase schedule landed at 38.7% MfmaUtil == old 2-barrier core.
//      Diagnosis: plain-C++ ds_reads after global_load_lds trigger the
//      backend's LDS-DMA alias hazard -> auto s_waitcnt vmcnt(0) before every
//      phase's reads -> the counted-vmcnt pipeline degenerates to drain-0
//      (m218: counted-vs-drain IS the 8-phase gain).
// R11: fragment reads -> inline-asm ds_read_b128 (opaque to hazard pass),
//      addresses precomputed (XOR swizzle decomposes into reg base + const
//      adds), explicit lgkmcnt(0)+sched_barrier(0) before each MFMA cluster
//      (rule #18), vmcnt(4) after P4's MFMA (overlap), barrier cadence kept.
//      Stage hazard schedule unchanged:
//        X.A1 <- X-1.P1   X.B1 <- X-1.P2   (other buffer, always safe)
//        X.B0 <- X-2.P3   (B regions last read in P2)
//        X.A0 <- X-2.P4   (A regions last read in P3)

#define S_LEN 2048
#define BATCH 4
#define DIN   1024
#define HDIM  1024
#define N3H   3072
#define NTOK  8192   // BATCH*S_LEN

typedef unsigned short u16;
typedef __attribute__((ext_vector_type(8))) short bf16x8;
typedef __attribute__((ext_vector_type(4))) float f32x4;
typedef __attribute__((ext_vector_type(16))) float f32x16;
typedef __attribute__((ext_vector_type(4))) unsigned short u16x4;

// ---------- bf16 helpers (bit ops, RN) ----------
__device__ __forceinline__ u16 f2bf(float x) {
  union { float f; unsigned u; } c; c.f = x;
  unsigned r = c.u + 0x7fffu + ((c.u >> 16) & 1u);
  return (u16)(r >> 16);
}
__device__ __forceinline__ float bf2f(u16 h) {
  union { unsigned u; float f; } c; c.u = ((unsigned)h) << 16;
  return c.f;
}

// ---------- async global->LDS, width 16 ----------
__device__ __forceinline__ void gload16(const void* g, void* lds) {
  auto* gp = reinterpret_cast<const __attribute__((address_space(1))) void*>(
      reinterpret_cast<uintptr_t>(g));
  auto* lp = reinterpret_cast<__attribute__((address_space(3))) void*>(
      (unsigned)reinterpret_cast<uintptr_t>(lds));
  __builtin_amdgcn_global_load_lds(gp, lp, 16, 0, 0);
}

// Stage a 128x64 bf16 tile (row-major, row stride ld elems) into swizzled LDS.
// Layout: element (row, kb=k/8) at byte row*128 + ((kb ^ (row&7))*16).
// 4-wave (256-thread) version: wave handles 4 instrs.
__device__ __forceinline__ void stage_tile(const u16* __restrict__ g, int ld,
                                           u16* lds, int wave, int lane) {
  const int rlane = lane >> 3;                       // 0..7: row within instr
  const int kb    = (lane & 7) ^ (rlane & 7);        // swizzled k-block
#pragma unroll
  for (int h = 0; h < 4; ++h) {
    const int instr = wave * 4 + h;                  // 0..15
    const u16* gp = g + (size_t)(instr * 8 + rlane) * ld + kb * 8;
    gload16(gp, (char*)lds + instr * 1024);
  }
}

// 8-wave (512-thread) version: wave handles 2 instrs; same LDS layout.
__device__ __forceinline__ void stage_half8(const u16* __restrict__ g, int ld,
                                            u16* lds, int wave, int lane) {
  const int rlane = lane >> 3;
  const int kb    = (lane & 7) ^ (rlane & 7);
#pragma unroll
  for (int h = 0; h < 2; ++h) {
    const int instr = wave * 2 + h;                  // 0..15
    const u16* gp = g + (size_t)(instr * 8 + rlane) * ld + kb * 8;
    gload16(gp, (char*)lds + instr * 1024);
  }
}

// 32x32x16 fragment fetch from swizzled [128][64] LDS tile (C++ path; used by
// the 128^2 plain core only).
__device__ __forceinline__ bf16x8 frag32(const u16* t, int wq, int sub, int kh,
                                         int lane) {
  const int r5   = lane & 31;
  const int row  = wq * 64 + sub * 32 + r5;
  const int slot = (kh * 2 + (lane >> 5)) ^ (r5 & 7);
  return *(const bf16x8*)(t + row * 64 + slot * 8);
}

// Inline-asm ds_read_b128: opaque to the compiler's LDS-DMA hazard pass, so
// no auto vmcnt(0) drain is inserted. Waits are done by hand (rule #18).
__device__ __forceinline__ bf16x8 dsr128(int addr) {
  bf16x8 r;
  asm volatile("ds_read_b128 %0, %1" : "=v"(r) : "v"(addr));
  return r;
}

__device__ __forceinline__ f32x16 mfma32(bf16x8 a, bf16x8 b, f32x16 c) {
  return __builtin_amdgcn_mfma_f32_32x32x16_bf16(a, b, c, 0, 0, 0);
}

// ---------- 3-pass operand selection over 48 K-tiles ----------
// pass 0: Ah*Bh, pass 1: Ah*Bl, pass 2: Al*Bh; k0 = (t&15)*64.
__device__ __forceinline__ const u16* selA(const u16* Ah, const u16* Al, int t) {
  return (t < 32) ? Ah : Al;
}
__device__ __forceinline__ const u16* selB(const u16* Bh, const u16* Bl, int t) {
  return ((t >> 4) == 1) ? Bl : Bh;
}

// ---------- one K-tile = 4 phases of the 256^2 8-phase schedule ----------
// LDS map (bytes): buf*65536 + {A0:0, A1:16384, B0:32768, B1:49152}.
// vA/vB: precomputed per-lane byte addresses [buf][kh] for the wave's A-half
// and B-quarter; per-read offsets are compile-time adds (wq*8192 + sub*4096
// for A, j*4096 for B).
// MODE: 2=steady (4 stages + vmcnt(4)), 1=last-but-one (2 stages + vmcnt(0)),
//       0=last (no stages).
template <int MODE, int BUF>
__device__ __forceinline__ void tile4(
    int t, u16* lds, f32x16 acc[4][2],
    const u16* __restrict__ Ah, const u16* __restrict__ Al,
    const u16* __restrict__ Bh, const u16* __restrict__ Bl,
    int lda, int ldb, const int (&vA)[2][4], const int (&vB)[2][4],
    int wave, int lane)
{
  bf16x8 fa[2][4], fb0[4], fb1[4];

  // ---- P1: quadrant (0,*): A rows 0-63; stage (t+1).A1 -> other buf ----
#pragma unroll
  for (int kh = 0; kh < 4; ++kh) {
    fa[0][kh] = dsr128(vA[BUF][kh]);           // wq=0 sub=0
    fa[1][kh] = dsr128(vA[BUF][kh] + 4096);    // wq=0 sub=1
    fb0[kh]   = dsr128(vB[BUF][kh]);           // j=0
  }
  if (MODE >= 1)
    stage_half8(selA(Ah, Al, t + 1) + (size_t)128 * lda + ((t + 1) & 15) * 64,
                lda, lds + (BUF ^ 1) * 32768 + 8192, wave, lane);
  __builtin_amdgcn_s_barrier();
  asm volatile("s_waitcnt lgkmcnt(0)" ::: "memory");
  __builtin_amdgcn_sched_barrier(0);
  __builtin_amdgcn_s_setprio(1);
#pragma unroll
  for (int kh = 0; kh < 4; ++kh) {
    acc[0][0] = mfma32(fa[0][kh], fb0[kh], acc[0][0]);
    acc[1][0] = mfma32(fa[1][kh], fb0[kh], acc[1][0]);
  }
  __builtin_amdgcn_s_setprio(0);
  __builtin_amdgcn_s_barrier();

  // ---- P2: B j=1; stage (t+1).B1 -> other buf ----
#pragma unroll
  for (int kh = 0; kh < 4; ++kh) fb1[kh] = dsr128(vB[BUF][kh] + 4096);
  if (MODE >= 1)
    stage_half8(selB(Bh, Bl, t + 1) + (size_t)128 * ldb + ((t + 1) & 15) * 64,
                ldb, lds + (BUF ^ 1) * 32768 + 24576, wave, lane);
  __builtin_amdgcn_s_barrier();
  asm volatile("s_waitcnt lgkmcnt(0)" ::: "memory");
  __builtin_amdgcn_sched_barrier(0);
  __builtin_amdgcn_s_setprio(1);
#pragma unroll
  for (int kh = 0; kh < 4; ++kh) {
    acc[0][1] = mfma32(fa[0][kh], fb1[kh], acc[0][1]);
    acc[1][1] = mfma32(fa[1][kh], fb1[kh], acc[1][1]);
  }
  __builtin_amdgcn_s_setprio(0);
  __builtin_amdgcn_s_barrier();

  // ---- P3: A rows 64-127; stage (t+2).B0 -> this buf (B reads done in P2) ----
#pragma unroll
  for (int kh = 0; kh < 4; ++kh) {
    fa[0][kh] = dsr128(vA[BUF][kh] + 8192);          // wq=1 sub=0
    fa[1][kh] = dsr128(vA[BUF][kh] + 8192 + 4096);   // wq=1 sub=1
  }
  if (MODE == 2)
    stage_half8(selB(Bh, Bl, t + 2) + ((t + 2) & 15) * 64, ldb,
                lds + BUF * 32768 + 16384, wave, lane);
  __builtin_amdgcn_s_barrier();
  asm volatile("s_waitcnt lgkmcnt(0)" ::: "memory");
  __builtin_amdgcn_sched_barrier(0);
  __builtin_amdgcn_s_setprio(1);
#pragma unroll
  for (int kh = 0; kh < 4; ++kh) {
    acc[2][0] = mfma32(fa[0][kh], fb0[kh], acc[2][0]);
    acc[3][0] = mfma32(fa[1][kh], fb0[kh], acc[3][0]);
  }
  __builtin_amdgcn_s_setprio(0);
  __builtin_amdgcn_s_barrier();

  // ---- P4: no reads; stage (t+2).A0 -> this buf (A reads done in P3);
  //      MFMA overlaps the counted vmcnt; closing barrier = collective point
  //      so next P1 reads see tile t+1 fully resident. ----
  if (MODE == 2)
    stage_half8(selA(Ah, Al, t + 2) + ((t + 2) & 15) * 64, lda,
                lds + BUF * 32768, wave, lane);
  __builtin_amdgcn_s_barrier();
  __builtin_amdgcn_s_setprio(1);
#pragma unroll
  for (int kh = 0; kh < 4; ++kh) {
    acc[2][1] = mfma32(fa[0][kh], fb1[kh], acc[2][1]);
    acc[3][1] = mfma32(fa[1][kh], fb1[kh], acc[3][1]);
  }
  __builtin_amdgcn_s_setprio(0);
  if (MODE == 2) asm volatile("s_waitcnt vmcnt(4)" ::: "memory");
  if (MODE == 1) asm volatile("s_waitcnt vmcnt(0)" ::: "memory");
  __builtin_amdgcn_s_barrier();
}

// ---------- 256x256 split GEMM: C = Ah*Bh^T + Ah*Bl^T + Al*Bh^T, K=1024 ----------
__device__ __forceinline__ void gemm256_split3(
    const u16* __restrict__ Ah, const u16* __restrict__ Al,
    const u16* __restrict__ Bh, const u16* __restrict__ Bl,
    int lda, int ldb, f32x16 acc[4][2], u16* lds,
    int wm, int wn, int wave, int lane)
{
#pragma unroll
  for (int a = 0; a < 4; ++a)
#pragma unroll
    for (int b = 0; b < 2; ++b)
#pragma unroll
      for (int r = 0; r < 16; ++r) acc[a][b][r] = 0.f;

  // Precompute swizzled per-lane LDS byte addresses.
  // frag byte addr = base + r5*128 + (((kh*2+hi)^x)<<4), x = r5&7, hi = lane>>5.
  // XOR decomposes: r5*128 + ((x^hi)<<4) then ^(kh<<5) (bits 4-6 disjoint from
  // r5*128's bits >=7). Region offsets are multiples of 4096 -> plain adds.
  const int r5 = lane & 31, hi = lane >> 5, x = r5 & 7;
  const int vb = r5 * 128 + ((x ^ hi) << 4);
  const int LB = (int)(unsigned)(uintptr_t)(void*)lds;
  int vA[2][4], vB[2][4];
#pragma unroll
  for (int b = 0; b < 2; ++b)
#pragma unroll
    for (int kh = 0; kh < 4; ++kh) {
      const int vk = vb ^ (kh << 5);
      vA[b][kh] = LB + b * 65536 + wm * 16384 + vk;
      vB[b][kh] = LB + b * 65536 + 32768 + (wn >> 1) * 16384 + (wn & 1) * 8192 + vk;
    }

  // prologue: t0 {A0,B0,A1,B1} + t1 {B0,A0}; retire t0, keep t1 pair in flight
  stage_half8(Ah, lda, lds, wave, lane);                              // t0.A0
  stage_half8(Bh, ldb, lds + 16384, wave, lane);                      // t0.B0
  stage_half8(Ah + (size_t)128 * lda, lda, lds + 8192, wave, lane);   // t0.A1
  stage_half8(Bh + (size_t)128 * ldb, ldb, lds + 24576, wave, lane);  // t0.B1
  stage_half8(Bh + 64, ldb, lds + 32768 + 16384, wave, lane);         // t1.B0
  stage_half8(Ah + 64, lda, lds + 32768, wave, lane);                 // t1.A0
  asm volatile("s_waitcnt vmcnt(4)" ::: "memory");
  __builtin_amdgcn_s_barrier();

#pragma unroll 1
  for (int t = 0; t < 46; t += 2) {
    tile4<2, 0>(t,     lds, acc, Ah, Al, Bh, Bl, lda, ldb, vA, vB, wave, lane);
    tile4<2, 1>(t + 1, lds, acc, Ah, Al, Bh, Bl, lda, ldb, vA, vB, wave, lane);
  }
  tile4<1, 0>(46, lds, acc, Ah, Al, Bh, Bl, lda, ldb, vA, vB, wave, lane);
  tile4<0, 1>(47, lds, acc, Ah, Al, Bh, Bl, lda, ldb, vA, vB, wave, lane);
}

// ---------- plain bf16 gemm_bt core (128^2, 256 threads) — proj_v / pv ----------
__device__ __forceinline__ void gemm_core_plain(
    const u16* __restrict__ A, const u16* __restrict__ B,
    int lda, int ldb, int K, f32x16 acc[2][2])
{
  __shared__ __align__(16) u16 lds[2 * 8192];
  u16* aT = lds; u16* bT = lds + 8192;
  const int tid  = threadIdx.x;
  const int wave = tid >> 6, lane = tid & 63;
  const int wm = wave >> 1, wn = wave & 1;

#pragma unroll
  for (int i = 0; i < 2; ++i)
#pragma unroll
    for (int j = 0; j < 2; ++j)
#pragma unroll
      for (int r = 0; r < 16; ++r) acc[i][j][r] = 0.f;

  for (int k0 = 0; k0 < K; k0 += 64) {
    stage_tile(A + k0, lda, aT, wave, lane);
    stage_tile(B + k0, ldb, bT, wave, lane);
    __syncthreads();
#pragma unroll
    for (int kh = 0; kh < 4; ++kh) {
      bf16x8 fa[2];
#pragma unroll
      for (int i = 0; i < 2; ++i) fa[i] = frag32(aT, wm, i, kh, lane);
#pragma unroll
      for (int j = 0; j < 2; ++j) {
        const bf16x8 fb = frag32(bT, wn, j, kh, lane);
#pragma unroll
        for (int i = 0; i < 2; ++i)
          acc[i][j] = __builtin_amdgcn_mfma_f32_32x32x16_bf16(fa[i], fb, acc[i][j], 0, 0, 0);
      }
    }
    __syncthreads();
  }
}

// C/D layout for 32x32 (HW-verified m74/m101):
//   col = lane&31, row = (reg&3) + 8*(reg>>2) + 4*(lane>>5)
#define ROW32(r, lane) (((r) & 3) + 8 * ((r) >> 2) + 4 * ((lane) >> 5))

// ---------- mask prep: detect bool(1B) vs int32(4B) repr, write additive bias ----------
__global__ void prep_mask_kernel(const unsigned char* __restrict__ m,
                                 float* __restrict__ bias) {
  __shared__ int isBool;
  if (threadIdx.x == 0) isBool = 0;
  __syncthreads();
  for (int i = threadIdx.x; i < NTOK; i += 256)
    if ((i & 3) && m[i]) isBool = 1;   // int32 repr of 0/1 has zero bytes at %4!=0
  __syncthreads();
  const int stride = isBool ? 1 : 4;
  const float ninf = -__builtin_inff();
  for (int i = threadIdx.x; i < NTOK; i += 256)
    bias[i] = m[(size_t)i * stride] ? ninf : 0.f;
}

// ---------- split fp32 -> bf16 hi/lo ----------
__global__ __launch_bounds__(256) void split_f32_kernel(
    const float* __restrict__ x, u16* __restrict__ hi, u16* __restrict__ lo) {
  const int i = (blockIdx.x * 256 + threadIdx.x) * 4;
  const f32x4 v = *(const f32x4*)(x + i);
  u16x4 h, l;
#pragma unroll
  for (int c = 0; c < 4; ++c) {
    h[c] = f2bf(v[c]);
    l[c] = f2bf(v[c] - bf2f(h[c]));
  }
  *(u16x4*)(hi + i) = h;
  *(u16x4*)(lo + i) = l;
}

// ---------- transpose + split W (DINxN3H -> N3HxDIN), 32x32 LDS tile ----------
__global__ __launch_bounds__(256) void splitWT_kernel(
    const float* __restrict__ W, u16* __restrict__ whi, u16* __restrict__ wlo) {
  __shared__ float tile[32][33];
  const int t = threadIdx.x;
  const int n0 = blockIdx.x * 32;   // 96 tiles over N3H
  const int d0 = blockIdx.y * 32;   // 32 tiles over DIN
  const int dr = t >> 3, nc = (t & 7) * 4;
  const f32x4 v = *(const f32x4*)(W + (size_t)(d0 + dr) * N3H + n0 + nc);
#pragma unroll
  for (int c = 0; c < 4; ++c) tile[dr][nc + c] = v[c];
  __syncthreads();
  const int nr = t >> 3, dc = (t & 7) * 4;
  u16x4 h, l;
#pragma unroll
  for (int c = 0; c < 4; ++c) {
    const float x = tile[dc + c][nr];
    h[c] = f2bf(x);
    l[c] = f2bf(x - bf2f(h[c]));
  }
  const size_t o = (size_t)(n0 + nr) * DIN + d0 + dc;
  *(u16x4*)(whi + o) = h;
  *(u16x4*)(wlo + o) = l;
}

// ---------- projection GEMM (Q,K thirds): 256^2 8-phase split ----------
__global__ __launch_bounds__(512, 2) void proj_qk256_kernel(
    const u16* __restrict__ Ahi, const u16* __restrict__ Alo,
    const u16* __restrict__ Whi, const u16* __restrict__ Wlo,
    const float* __restrict__ bias,
    u16* __restrict__ qhi, u16* __restrict__ qlo,
    u16* __restrict__ khi, u16* __restrict__ klo)
{
  __shared__ __align__(16) u16 lds[2 * 4 * 8192];   // 128 KiB
  const int bx = blockIdx.x, by = blockIdx.y;  // bx: 8 tiles over cols 0..2047
  const int tid = threadIdx.x, wave = tid >> 6, lane = tid & 63;
  const int wm = wave >> 2, wn = wave & 3;

  f32x16 acc[4][2];
  gemm256_split3(Ahi + (size_t)by * 256 * DIN, Alo + (size_t)by * 256 * DIN,
                 Whi + (size_t)bx * 256 * DIN, Wlo + (size_t)bx * 256 * DIN,
                 DIN, DIN, acc, lds, wm, wn, wave, lane);

#pragma unroll
  for (int a = 0; a < 4; ++a) {
#pragma unroll
    for (int b = 0; b < 2; ++b) {
#pragma unroll
      for (int r = 0; r < 16; ++r) {
        const int row = by * 256 + wm * 128 + a * 32 + ROW32(r, lane);  // token
        const int col = bx * 256 + wn * 64 + b * 32 + (lane & 31);      // 0..2047
        const float v = acc[a][b][r] + bias[col];
        const u16 h = f2bf(v);
        const u16 l = f2bf(v - bf2f(h));
        if (col < HDIM) {                       // Q (block-uniform branch)
          const size_t idx = (size_t)row * HDIM + col;
          qhi[idx] = h; qlo[idx] = l;
        } else {                                // K
          const size_t idx = (size_t)row * HDIM + (col - HDIM);
          khi[idx] = h; klo[idx] = l;
        }
      }
    }
  }
}

// ---------- projection GEMM (V third): plain bf16, writes V transposed ----------
__global__ __launch_bounds__(256, 2) void proj_v_kernel(
    const u16* __restrict__ Ahi, const u16* __restrict__ Whi,
    const float* __restrict__ bias, u16* __restrict__ vt)
{
  const int bx = blockIdx.x, by = blockIdx.y;  // bx over 8 tiles (cols 2048..3071)
  f32x16 acc[2][2];
  gemm_core_plain(Ahi + (size_t)by * 128 * DIN,
                  Whi + (size_t)(2048 + bx * 128) * DIN,
                  DIN, DIN, DIN, acc);
  const int lane = threadIdx.x & 63, wave = threadIdx.x >> 6;
  const int wm = wave >> 1, wn = wave & 1;
#pragma unroll
  for (int i = 0; i < 2; ++i) {
#pragma unroll
    for (int j = 0; j < 2; ++j) {
#pragma unroll
      for (int r = 0; r < 16; ++r) {
        const int row = by * 128 + wm * 64 + i * 32 + ROW32(r, lane);  // token
        const int b = row >> 11, s = row & 2047;
        const int hcol = bx * 128 + wn * 64 + j * 32 + (lane & 31);    // 0..1023
        const float v = acc[i][j][r] + bias[2 * HDIM + hcol];
        vt[((size_t)b * HDIM + hcol) * S_LEN + s] = f2bf(v);
      }
    }
  }
}

// ---------- scores GEMM: sc = 32 * Q @ K^T + maskbias(key), 256^2 8-phase ----------
__global__ __launch_bounds__(512, 2) void scores256_kernel(
    const u16* __restrict__ qhi, const u16* __restrict__ qlo,
    const u16* __restrict__ khi, const u16* __restrict__ klo,
    const float* __restrict__ maskbias, float* __restrict__ scores)
{
  __shared__ __align__(16) u16 lds[2 * 4 * 8192];   // 128 KiB
  const int id = blockIdx.x;            // 0..255
  const int b  = id >> 6;               // batch
  const int by = (id >> 3) & 7;         // Q-tile
  const int bx = id & 7;                // K-tile
  const int tid = threadIdx.x, wave = tid >> 6, lane = tid & 63;
  const int wm = wave >> 2, wn = wave & 3;

  f32x16 acc[4][2];
  const size_t qoff = ((size_t)b * S_LEN + by * 256) * HDIM;
  const size_t koff = ((size_t)b * S_LEN + bx * 256) * HDIM;
  gemm256_split3(qhi + qoff, qlo + qoff, khi + koff, klo + koff,
                 HDIM, HDIM, acc, lds, wm, wn, wave, lane);

#pragma unroll
  for (int a = 0; a < 4; ++a) {
#pragma unroll
    for (int bj = 0; bj < 2; ++bj) {
#pragma unroll
      for (int r = 0; r < 16; ++r) {
        const int q   = by * 256 + wm * 128 + a * 32 + ROW32(r, lane);
        const int key = bx * 256 + wn * 64 + bj * 32 + (lane & 31);
        scores[((size_t)b * S_LEN + q) * S_LEN + key] =
            32.0f * acc[a][bj][r] + maskbias[b * S_LEN + key];
      }
    }
  }
}

// ---------- softmax: one wave per row, barrier-free, in-place fp32 -> bf16 ----------
__global__ __launch_bounds__(256) void softmax_kernel(float* __restrict__ scores) {
  const int wave = threadIdx.x >> 6, lane = threadIdx.x & 63;
  const int row = blockIdx.x * 4 + wave;
  float* srow = scores + (size_t)row * S_LEN;

  f32x4 v[8];
#pragma unroll
  for (int c = 0; c < 8; ++c) v[c] = ((const f32x4*)srow)[c * 64 + lane];

  float m = -__builtin_inff();
#pragma unroll
  for (int c = 0; c < 8; ++c)
    m = fmaxf(m, fmaxf(fmaxf(v[c][0], v[c][1]), fmaxf(v[c][2], v[c][3])));
#pragma unroll
  for (int o = 32; o > 0; o >>= 1) m = fmaxf(m, __shfl_xor(m, o));

  float s = 0.f;
#pragma unroll
  for (int c = 0; c < 8; ++c) {
#pragma unroll
    for (int e = 0; e < 4; ++e) {
      v[c][e] = __expf(v[c][e] - m);
      s += v[c][e];
    }
  }
#pragma unroll
  for (int o = 32; o > 0; o >>= 1) s += __shfl_xor(s, o);
  const float inv = 1.0f / s;

  u16* prow = (u16*)srow;   // bf16 row at same base; valid elems 0..2047, stride 4096
#pragma unroll
  for (int c = 0; c < 8; ++c) {
    u16x4 o4 = { f2bf(v[c][0] * inv), f2bf(v[c][1] * inv),
                 f2bf(v[c][2] * inv), f2bf(v[c][3] * inv) };
    ((u16x4*)prow)[c * 64 + lane] = o4;
  }
}

// ---------- PV GEMM: out = P @ Vt^T ----------
// XCD-aware decode: region r = xcd (2x4 regions of 4x4 per batch),
// Vt stripes pinned per XCD.
__global__ __launch_bounds__(256, 2) void pv_kernel(
    const u16* __restrict__ P, const u16* __restrict__ vt, float* __restrict__ out)
{
  const int id   = blockIdx.x;          // 0..511
  const int xcd  = id & 7;
  const int s    = id >> 3;             // 0..63
  const int b    = s >> 4;              // batch 0..3
  const int slot = s & 15;
  const int bx   = (xcd & 1) * 4 + (slot & 3);   // H-tile 0..7
  const int by   = (xcd >> 1) * 4 + (slot >> 2); // Q-tile 0..15

  f32x16 acc[2][2];
  gemm_core_plain(P + ((size_t)b * S_LEN + by * 128) * (2 * S_LEN),
                  vt + ((size_t)b * HDIM + bx * 128) * S_LEN,
                  2 * S_LEN, S_LEN, S_LEN, acc);
  const int lane = threadIdx.x & 63, wave = threadIdx.x >> 6;
  const int wm = wave >> 1, wn = wave & 1;
#pragma unroll
  for (int i = 0; i < 2; ++i) {
#pragma unroll
    for (int j = 0; j < 2; ++j) {
#pragma unroll
      for (int r = 0; r < 16; ++r) {
        const int q = by * 128 + wm * 64 + i * 32 + ROW32(r, lane);
        const int h = bx * 128 + wn * 64 + j * 32 + (lane & 31);
        out[((size_t)b * S_LEN + q) * HDIM + h] = acc[i][j][r];
      }
    }
  }
}

extern "C" void kernel_launch(void* const* d_in, const int* in_sizes, int n_in,
                              void* d_out, int out_size, void* d_ws, size_t ws_size,
                              hipStream_t stream)
{
  const float* qkv  = (const float*)d_in[0];
  const void*  mask = d_in[1];
  const float* W    = (const float*)d_in[2];
  const float* bias = (const float*)d_in[3];
  float* out = (float*)d_out;
  char* ws = (char*)d_ws;

  const size_t off_mask = 0;
  const size_t off_Whi  = 32768;
  const size_t off_Wlo  = off_Whi + (size_t)N3H * DIN * 2;
  const size_t off_Qhi  = off_Wlo + (size_t)N3H * DIN * 2;
  const size_t off_Qlo  = off_Qhi + (size_t)NTOK * HDIM * 2;
  const size_t off_Khi  = off_Qlo + (size_t)NTOK * HDIM * 2;
  const size_t off_Klo  = off_Khi + (size_t)NTOK * HDIM * 2;
  const size_t off_Vt   = off_Klo + (size_t)NTOK * HDIM * 2;
  const size_t off_A    = off_Vt + (size_t)NTOK * HDIM * 2;
  const size_t off_Alo  = off_A + (size_t)NTOK * DIN * 2;
  const size_t off_sc   = off_A;  // scores (67MB) overlay A-split (dead after proj)
  // total ws requirement: off_A + BATCH*S*S*4 = ~156 MiB

  float* maskbias = (float*)(ws + off_mask);
  u16* Whi = (u16*)(ws + off_Whi);  u16* Wlo = (u16*)(ws + off_Wlo);
  u16* Qhi = (u16*)(ws + off_Qhi);  u16* Qlo = (u16*)(ws + off_Qlo);
  u16* Khi = (u16*)(ws + off_Khi);  u16* Klo = (u16*)(ws + off_Klo);
  u16* Vt  = (u16*)(ws + off_Vt);
  u16* Ahi = (u16*)(ws + off_A);    u16* Alo = (u16*)(ws + off_Alo);
  float* scores = (float*)(ws + off_sc);

  prep_mask_kernel<<<1, 256, 0, stream>>>((const unsigned char*)mask, maskbias);
  split_f32_kernel<<<NTOK * DIN / 1024, 256, 0, stream>>>(qkv, Ahi, Alo);
  splitWT_kernel<<<dim3(N3H / 32, DIN / 32), 256, 0, stream>>>(W, Whi, Wlo);
  proj_qk256_kernel<<<dim3(2 * HDIM / 256, NTOK / 256), 512, 0, stream>>>(
      Ahi, Alo, Whi, Wlo, bias, Qhi, Qlo, Khi, Klo);
  proj_v_kernel<<<dim3(HDIM / 128, NTOK / 128, 1), 256, 0, stream>>>(
      Ahi, Whi, bias, Vt);
  scores256_kernel<<<64 * BATCH, 512, 0, stream>>>(
      Qhi, Qlo, Khi, Klo, maskbias, scores);
  softmax_kernel<<<NTOK / 4, 256, 0, stream>>>(scores);
  pv_kernel<<<8 * 16 * BATCH, 256, 0, stream>>>(
      (const u16*)scores, Vt, out);
}

// Round 3
// 410.742 us; speedup vs baseline: 1.0382x; 1.0382x over previous
//
#include <hip/hip_runtime.h>
#include <stdint.h>

// Problem: B=4, S=2048, D_IN=1024, H=1024; fp32 in/out.
// Pipeline: [prep_mask] [split qkv->bf16 hi/lo] [split+transpose W (LDS tile)]
//           [proj_qk 256^2 split-GEMM -> Qhi/Qlo/Khi/Klo]
//           [proj_v GEMM plain bf16 -> Vt]
//           [scores 256^2 split-GEMM *32 + maskbias -> fp32 scores]
//           [softmax per-wave in-place -> bf16 P]   [PV GEMM bf16 -> out]
// R10/R11: 8-phase 256^2 schedule (8 barriers/K-tile) pinned at 37.7-38.7%
//      MfmaUtil == the old 2-barrier 128^2 core. Counter evidence: asm-opaque
//      reads changed NOTHING -> compiler drains were not the gate. Budget per
//      K-tile per CU: MFMA 2070cyc + LDS-read 1540 + stage 510 = 4100, measured
//      5850 -> ~1700cyc sync overhead per tile (8 barrier crossings for 64-cyc
//      MFMA clusters) and zero read<->MFMA overlap (per-phase realignment).
// R12: barrier granularity is the variable. 2 barriers + 1 counted vmcnt per
//      K-tile; the whole 24-read + 32-MFMA body is ONE wave-slip region so
//      co-resident waves overlap LDS reads with MFMA (m114 mechanism).
//      Hazards: B2 => all reads of buf done => stage(t+2->buf) safe;
//      vmcnt(8) after stage(t+2) retires stage(t+1); B1 => t+1 resident.
//      No vmcnt(0)/lgkm drain inside the loop; 8 independent acc chains.

#define S_LEN 2048
#define BATCH 4
#define DIN   1024
#define HDIM  1024
#define N3H   3072
#define NTOK  8192   // BATCH*S_LEN

typedef unsigned short u16;
typedef __attribute__((ext_vector_type(8))) short bf16x8;
typedef __attribute__((ext_vector_type(4))) float f32x4;
typedef __attribute__((ext_vector_type(16))) float f32x16;
typedef __attribute__((ext_vector_type(4))) unsigned short u16x4;

// ---------- bf16 helpers (bit ops, RN) ----------
__device__ __forceinline__ u16 f2bf(float x) {
  union { float f; unsigned u; } c; c.f = x;
  unsigned r = c.u + 0x7fffu + ((c.u >> 16) & 1u);
  return (u16)(r >> 16);
}
__device__ __forceinline__ float bf2f(u16 h) {
  union { unsigned u; float f; } c; c.u = ((unsigned)h) << 16;
  return c.f;
}

// ---------- async global->LDS, width 16 ----------
__device__ __forceinline__ void gload16(const void* g, void* lds) {
  auto* gp = reinterpret_cast<const __attribute__((address_space(1))) void*>(
      reinterpret_cast<uintptr_t>(g));
  auto* lp = reinterpret_cast<__attribute__((address_space(3))) void*>(
      (unsigned)reinterpret_cast<uintptr_t>(lds));
  __builtin_amdgcn_global_load_lds(gp, lp, 16, 0, 0);
}

// Stage a 128x64 bf16 tile (row-major, row stride ld elems) into swizzled LDS.
// Layout: element (row, kb=k/8) at byte row*128 + ((kb ^ (row&7))*16).
// 4-wave (256-thread) version: wave handles 4 instrs.
__device__ __forceinline__ void stage_tile(const u16* __restrict__ g, int ld,
                                           u16* lds, int wave, int lane) {
  const int rlane = lane >> 3;                       // 0..7: row within instr
  const int kb    = (lane & 7) ^ (rlane & 7);        // swizzled k-block
#pragma unroll
  for (int h = 0; h < 4; ++h) {
    const int instr = wave * 4 + h;                  // 0..15
    const u16* gp = g + (size_t)(instr * 8 + rlane) * ld + kb * 8;
    gload16(gp, (char*)lds + instr * 1024);
  }
}

// 8-wave (512-thread) version: wave handles 2 instrs; same LDS layout.
__device__ __forceinline__ void stage_half8(const u16* __restrict__ g, int ld,
                                            u16* lds, int wave, int lane) {
  const int rlane = lane >> 3;
  const int kb    = (lane & 7) ^ (rlane & 7);
#pragma unroll
  for (int h = 0; h < 2; ++h) {
    const int instr = wave * 2 + h;                  // 0..15
    const u16* gp = g + (size_t)(instr * 8 + rlane) * ld + kb * 8;
    gload16(gp, (char*)lds + instr * 1024);
  }
}

// Stage a full 256x64 A-tile + 256x64 B-tile (8 gloads per wave).
__device__ __forceinline__ void stage_tile8(
    const u16* __restrict__ A, const u16* __restrict__ B, int lda, int ldb,
    u16* ldsbuf, int wave, int lane) {
  stage_half8(A, lda, ldsbuf, wave, lane);                              // A0
  stage_half8(A + (size_t)128 * lda, lda, ldsbuf + 8192, wave, lane);   // A1
  stage_half8(B, ldb, ldsbuf + 16384, wave, lane);                      // B0
  stage_half8(B + (size_t)128 * ldb, ldb, ldsbuf + 24576, wave, lane);  // B1
}

// 32x32x16 fragment fetch from swizzled [128][64] LDS tile (C++ path; used by
// the 128^2 plain core only).
__device__ __forceinline__ bf16x8 frag32(const u16* t, int wq, int sub, int kh,
                                         int lane) {
  const int r5   = lane & 31;
  const int row  = wq * 64 + sub * 32 + r5;
  const int slot = (kh * 2 + (lane >> 5)) ^ (r5 & 7);
  return *(const bf16x8*)(t + row * 64 + slot * 8);
}

// Inline-asm ds_read_b128: opaque to the compiler's LDS-DMA hazard pass, so
// no auto vmcnt(0) drain is inserted. Waits are done by hand (rule #18).
__device__ __forceinline__ bf16x8 dsr128(int addr) {
  bf16x8 r;
  asm volatile("ds_read_b128 %0, %1" : "=v"(r) : "v"(addr));
  return r;
}

__device__ __forceinline__ f32x16 mfma32(bf16x8 a, bf16x8 b, f32x16 c) {
  return __builtin_amdgcn_mfma_f32_32x32x16_bf16(a, b, c, 0, 0, 0);
}

// ---------- 3-pass operand selection over 48 K-tiles ----------
// pass 0: Ah*Bh, pass 1: Ah*Bl, pass 2: Al*Bh; k0 = (t&15)*64.
__device__ __forceinline__ const u16* selA(const u16* Ah, const u16* Al, int t) {
  return (t < 32) ? Ah : Al;
}
__device__ __forceinline__ const u16* selB(const u16* Bh, const u16* Bl, int t) {
  return ((t >> 4) == 1) ? Bl : Bh;
}

// ---------- one K-tile, 2-barrier counted schedule ----------
// LDS map (bytes): buf*65536 + {A0:0, A1:16384, B0:32768, B1:49152}.
// vA/vB: precomputed per-lane byte addresses [buf][kh]; sub-tile offsets are
// compile-time adds (A: +a*4096 for rows wm*128+a*32; B: +j*4096).
// MODE: 2=steady (stage t+2, vmcnt(8)), 1=t=46 (no stage, vmcnt(0)), 0=last.
template <int MODE, int BUF>
__device__ __forceinline__ void tileK(
    int t, u16* lds, f32x16 acc[4][2],
    const u16* __restrict__ Ah, const u16* __restrict__ Al,
    const u16* __restrict__ Bh, const u16* __restrict__ Bl,
    int lda, int ldb, const int (&vA)[2][4], const int (&vB)[2][4],
    int wave, int lane)
{
  bf16x8 fb0[4], fb1[4], fa[2][4];

  // ---- read cluster 1: all B + A rows 0-63 (16 ds_reads) ----
#pragma unroll
  for (int kh = 0; kh < 4; ++kh) {
    fb0[kh]   = dsr128(vB[BUF][kh]);
    fb1[kh]   = dsr128(vB[BUF][kh] + 4096);
    fa[0][kh] = dsr128(vA[BUF][kh]);
    fa[1][kh] = dsr128(vA[BUF][kh] + 4096);
  }
  asm volatile("s_waitcnt lgkmcnt(0)" ::: "memory");
  __builtin_amdgcn_sched_barrier(0);
  __builtin_amdgcn_s_setprio(1);
#pragma unroll
  for (int kh = 0; kh < 4; ++kh) {
    acc[0][0] = mfma32(fa[0][kh], fb0[kh], acc[0][0]);
    acc[1][0] = mfma32(fa[1][kh], fb0[kh], acc[1][0]);
    acc[0][1] = mfma32(fa[0][kh], fb1[kh], acc[0][1]);
    acc[1][1] = mfma32(fa[1][kh], fb1[kh], acc[1][1]);
  }
  __builtin_amdgcn_s_setprio(0);

  // ---- read cluster 2: A rows 64-127 (8 ds_reads) ----
#pragma unroll
  for (int kh = 0; kh < 4; ++kh) {
    fa[0][kh] = dsr128(vA[BUF][kh] + 8192);
    fa[1][kh] = dsr128(vA[BUF][kh] + 12288);
  }
  asm volatile("s_waitcnt lgkmcnt(0)" ::: "memory");
  __builtin_amdgcn_sched_barrier(0);
  __builtin_amdgcn_s_setprio(1);
#pragma unroll
  for (int kh = 0; kh < 4; ++kh) {
    acc[2][0] = mfma32(fa[0][kh], fb0[kh], acc[2][0]);
    acc[3][0] = mfma32(fa[1][kh], fb0[kh], acc[3][0]);
    acc[2][1] = mfma32(fa[0][kh], fb1[kh], acc[2][1]);
    acc[3][1] = mfma32(fa[1][kh], fb1[kh], acc[3][1]);
  }
  __builtin_amdgcn_s_setprio(0);

  // ---- B2: all waves' reads of BUF done -> stage t+2 into BUF is safe ----
  __builtin_amdgcn_s_barrier();
  if (MODE == 2) {
    stage_tile8(selA(Ah, Al, t + 2) + ((t + 2) & 15) * 64,
                selB(Bh, Bl, t + 2) + ((t + 2) & 15) * 64,
                lda, ldb, lds + BUF * 32768, wave, lane);
    asm volatile("s_waitcnt vmcnt(8)" ::: "memory");   // retire stage(t+1)
  }
  if (MODE == 1) asm volatile("s_waitcnt vmcnt(0)" ::: "memory");
  // ---- B1: tile t+1 resident block-wide ----
  __builtin_amdgcn_s_barrier();
}

// ---------- 256x256 split GEMM: C = Ah*Bh^T + Ah*Bl^T + Al*Bh^T, K=1024 ----------
__device__ __forceinline__ void gemm256_split3(
    const u16* __restrict__ Ah, const u16* __restrict__ Al,
    const u16* __restrict__ Bh, const u16* __restrict__ Bl,
    int lda, int ldb, f32x16 acc[4][2], u16* lds,
    int wm, int wn, int wave, int lane)
{
#pragma unroll
  for (int a = 0; a < 4; ++a)
#pragma unroll
    for (int b = 0; b < 2; ++b)
#pragma unroll
      for (int r = 0; r < 16; ++r) acc[a][b][r] = 0.f;

  // Precompute swizzled per-lane LDS byte addresses.
  // frag byte addr = base + r5*128 + (((kh*2+hi)^x)<<4), x = r5&7, hi = lane>>5.
  // XOR decomposes: r5*128 + ((x^hi)<<4) then ^(kh<<5) (bits 4-6 disjoint from
  // r5*128's bits >=7). Region offsets are multiples of 4096 -> plain adds.
  const int r5 = lane & 31, hi = lane >> 5, x = r5 & 7;
  const int vb = r5 * 128 + ((x ^ hi) << 4);
  const int LB = (int)(unsigned)(uintptr_t)(void*)lds;
  int vA[2][4], vB[2][4];
#pragma unroll
  for (int b = 0; b < 2; ++b)
#pragma unroll
    for (int kh = 0; kh < 4; ++kh) {
      const int vk = vb ^ (kh << 5);
      vA[b][kh] = LB + b * 65536 + wm * 16384 + vk;
      vB[b][kh] = LB + b * 65536 + 32768 + wn * 8192 + vk;
    }

  // prologue: stage t0 -> buf0, t1 -> buf1; retire t0, keep t1 in flight
  stage_tile8(Ah, Bh, lda, ldb, lds, wave, lane);            // t0 (k0=0)
  stage_tile8(Ah + 64, Bh + 64, lda, ldb, lds + 32768, wave, lane);  // t1
  asm volatile("s_waitcnt vmcnt(8)" ::: "memory");
  __builtin_amdgcn_s_barrier();

#pragma unroll 1
  for (int t = 0; t < 46; t += 2) {
    tileK<2, 0>(t,     lds, acc, Ah, Al, Bh, Bl, lda, ldb, vA, vB, wave, lane);
    tileK<2, 1>(t + 1, lds, acc, Ah, Al, Bh, Bl, lda, ldb, vA, vB, wave, lane);
  }
  tileK<1, 0>(46, lds, acc, Ah, Al, Bh, Bl, lda, ldb, vA, vB, wave, lane);
  tileK<0, 1>(47, lds, acc, Ah, Al, Bh, Bl, lda, ldb, vA, vB, wave, lane);
}

// ---------- plain bf16 gemm_bt core (128^2, 256 threads) — proj_v / pv ----------
__device__ __forceinline__ void gemm_core_plain(
    const u16* __restrict__ A, const u16* __restrict__ B,
    int lda, int ldb, int K, f32x16 acc[2][2])
{
  __shared__ __align__(16) u16 lds[2 * 8192];
  u16* aT = lds; u16* bT = lds + 8192;
  const int tid  = threadIdx.x;
  const int wave = tid >> 6, lane = tid & 63;
  const int wm = wave >> 1, wn = wave & 1;

#pragma unroll
  for (int i = 0; i < 2; ++i)
#pragma unroll
    for (int j = 0; j < 2; ++j)
#pragma unroll
      for (int r = 0; r < 16; ++r) acc[i][j][r] = 0.f;

  for (int k0 = 0; k0 < K; k0 += 64) {
    stage_tile(A + k0, lda, aT, wave, lane);
    stage_tile(B + k0, ldb, bT, wave, lane);
    __syncthreads();
#pragma unroll
    for (int kh = 0; kh < 4; ++kh) {
      bf16x8 fa[2];
#pragma unroll
      for (int i = 0; i < 2; ++i) fa[i] = frag32(aT, wm, i, kh, lane);
#pragma unroll
      for (int j = 0; j < 2; ++j) {
        const bf16x8 fb = frag32(bT, wn, j, kh, lane);
#pragma unroll
        for (int i = 0; i < 2; ++i)
          acc[i][j] = __builtin_amdgcn_mfma_f32_32x32x16_bf16(fa[i], fb, acc[i][j], 0, 0, 0);
      }
    }
    __syncthreads();
  }
}

// C/D layout for 32x32 (HW-verified m74/m101):
//   col = lane&31, row = (reg&3) + 8*(reg>>2) + 4*(lane>>5)
#define ROW32(r, lane) (((r) & 3) + 8 * ((r) >> 2) + 4 * ((lane) >> 5))

// ---------- mask prep: detect bool(1B) vs int32(4B) repr, write additive bias ----------
__global__ void prep_mask_kernel(const unsigned char* __restrict__ m,
                                 float* __restrict__ bias) {
  __shared__ int isBool;
  if (threadIdx.x == 0) isBool = 0;
  __syncthreads();
  for (int i = threadIdx.x; i < NTOK; i += 256)
    if ((i & 3) && m[i]) isBool = 1;   // int32 repr of 0/1 has zero bytes at %4!=0
  __syncthreads();
  const int stride = isBool ? 1 : 4;
  const float ninf = -__builtin_inff();
  for (int i = threadIdx.x; i < NTOK; i += 256)
    bias[i] = m[(size_t)i * stride] ? ninf : 0.f;
}

// ---------- split fp32 -> bf16 hi/lo ----------
__global__ __launch_bounds__(256) void split_f32_kernel(
    const float* __restrict__ x, u16* __restrict__ hi, u16* __restrict__ lo) {
  const int i = (blockIdx.x * 256 + threadIdx.x) * 4;
  const f32x4 v = *(const f32x4*)(x + i);
  u16x4 h, l;
#pragma unroll
  for (int c = 0; c < 4; ++c) {
    h[c] = f2bf(v[c]);
    l[c] = f2bf(v[c] - bf2f(h[c]));
  }
  *(u16x4*)(hi + i) = h;
  *(u16x4*)(lo + i) = l;
}

// ---------- transpose + split W (DINxN3H -> N3HxDIN), 32x32 LDS tile ----------
__global__ __launch_bounds__(256) void splitWT_kernel(
    const float* __restrict__ W, u16* __restrict__ whi, u16* __restrict__ wlo) {
  __shared__ float tile[32][33];
  const int t = threadIdx.x;
  const int n0 = blockIdx.x * 32;   // 96 tiles over N3H
  const int d0 = blockIdx.y * 32;   // 32 tiles over DIN
  const int dr = t >> 3, nc = (t & 7) * 4;
  const f32x4 v = *(const f32x4*)(W + (size_t)(d0 + dr) * N3H + n0 + nc);
#pragma unroll
  for (int c = 0; c < 4; ++c) tile[dr][nc + c] = v[c];
  __syncthreads();
  const int nr = t >> 3, dc = (t & 7) * 4;
  u16x4 h, l;
#pragma unroll
  for (int c = 0; c < 4; ++c) {
    const float x = tile[dc + c][nr];
    h[c] = f2bf(x);
    l[c] = f2bf(x - bf2f(h[c]));
  }
  const size_t o = (size_t)(n0 + nr) * DIN + d0 + dc;
  *(u16x4*)(whi + o) = h;
  *(u16x4*)(wlo + o) = l;
}

// ---------- projection GEMM (Q,K thirds): 256^2 split ----------
__global__ __launch_bounds__(512, 2) void proj_qk256_kernel(
    const u16* __restrict__ Ahi, const u16* __restrict__ Alo,
    const u16* __restrict__ Whi, const u16* __restrict__ Wlo,
    const float* __restrict__ bias,
    u16* __restrict__ qhi, u16* __restrict__ qlo,
    u16* __restrict__ khi, u16* __restrict__ klo)
{
  __shared__ __align__(16) u16 lds[2 * 4 * 8192];   // 128 KiB
  const int bx = blockIdx.x, by = blockIdx.y;  // bx: 8 tiles over cols 0..2047
  const int tid = threadIdx.x, wave = tid >> 6, lane = tid & 63;
  const int wm = wave >> 2, wn = wave & 3;

  f32x16 acc[4][2];
  gemm256_split3(Ahi + (size_t)by * 256 * DIN, Alo + (size_t)by * 256 * DIN,
                 Whi + (size_t)bx * 256 * DIN, Wlo + (size_t)bx * 256 * DIN,
                 DIN, DIN, acc, lds, wm, wn, wave, lane);

#pragma unroll
  for (int a = 0; a < 4; ++a) {
#pragma unroll
    for (int b = 0; b < 2; ++b) {
#pragma unroll
      for (int r = 0; r < 16; ++r) {
        const int row = by * 256 + wm * 128 + a * 32 + ROW32(r, lane);  // token
        const int col = bx * 256 + wn * 64 + b * 32 + (lane & 31);      // 0..2047
        const float v = acc[a][b][r] + bias[col];
        const u16 h = f2bf(v);
        const u16 l = f2bf(v - bf2f(h));
        if (col < HDIM) {                       // Q (block-uniform branch)
          const size_t idx = (size_t)row * HDIM + col;
          qhi[idx] = h; qlo[idx] = l;
        } else {                                // K
          const size_t idx = (size_t)row * HDIM + (col - HDIM);
          khi[idx] = h; klo[idx] = l;
        }
      }
    }
  }
}

// ---------- projection GEMM (V third): plain bf16, writes V transposed ----------
__global__ __launch_bounds__(256, 2) void proj_v_kernel(
    const u16* __restrict__ Ahi, const u16* __restrict__ Whi,
    const float* __restrict__ bias, u16* __restrict__ vt)
{
  const int bx = blockIdx.x, by = blockIdx.y;  // bx over 8 tiles (cols 2048..3071)
  f32x16 acc[2][2];
  gemm_core_plain(Ahi + (size_t)by * 128 * DIN,
                  Whi + (size_t)(2048 + bx * 128) * DIN,
                  DIN, DIN, DIN, acc);
  const int lane = threadIdx.x & 63, wave = threadIdx.x >> 6;
  const int wm = wave >> 1, wn = wave & 1;
#pragma unroll
  for (int i = 0; i < 2; ++i) {
#pragma unroll
    for (int j = 0; j < 2; ++j) {
#pragma unroll
      for (int r = 0; r < 16; ++r) {
        const int row = by * 128 + wm * 64 + i * 32 + ROW32(r, lane);  // token
        const int b = row >> 11, s = row & 2047;
        const int hcol = bx * 128 + wn * 64 + j * 32 + (lane & 31);    // 0..1023
        const float v = acc[i][j][r] + bias[2 * HDIM + hcol];
        vt[((size_t)b * HDIM + hcol) * S_LEN + s] = f2bf(v);
      }
    }
  }
}

// ---------- scores GEMM: sc = 32 * Q @ K^T + maskbias(key), 256^2 ----------
__global__ __launch_bounds__(512, 2) void scores256_kernel(
    const u16* __restrict__ qhi, const u16* __restrict__ qlo,
    const u16* __restrict__ khi, const u16* __restrict__ klo,
    const float* __restrict__ maskbias, float* __restrict__ scores)
{
  __shared__ __align__(16) u16 lds[2 * 4 * 8192];   // 128 KiB
  const int id = blockIdx.x;            // 0..255
  const int b  = id >> 6;               // batch
  const int by = (id >> 3) & 7;         // Q-tile
  const int bx = id & 7;                // K-tile
  const int tid = threadIdx.x, wave = tid >> 6, lane = tid & 63;
  const int wm = wave >> 2, wn = wave & 3;

  f32x16 acc[4][2];
  const size_t qoff = ((size_t)b * S_LEN + by * 256) * HDIM;
  const size_t koff = ((size_t)b * S_LEN + bx * 256) * HDIM;
  gemm256_split3(qhi + qoff, qlo + qoff, khi + koff, klo + koff,
                 HDIM, HDIM, acc, lds, wm, wn, wave, lane);

#pragma unroll
  for (int a = 0; a < 4; ++a) {
#pragma unroll
    for (int bj = 0; bj < 2; ++bj) {
#pragma unroll
      for (int r = 0; r < 16; ++r) {
        const int q   = by * 256 + wm * 128 + a * 32 + ROW32(r, lane);
        const int key = bx * 256 + wn * 64 + bj * 32 + (lane & 31);
        scores[((size_t)b * S_LEN + q) * S_LEN + key] =
            32.0f * acc[a][bj][r] + maskbias[b * S_LEN + key];
      }
    }
  }
}

// ---------- softmax: one wave per row, barrier-free, in-place fp32 -> bf16 ----------
__global__ __launch_bounds__(256) void softmax_kernel(float* __restrict__ scores) {
  const int wave = threadIdx.x >> 6, lane = threadIdx.x & 63;
  const int row = blockIdx.x * 4 + wave;
  float* srow = scores + (size_t)row * S_LEN;

  f32x4 v[8];
#pragma unroll
  for (int c = 0; c < 8; ++c) v[c] = ((const f32x4*)srow)[c * 64 + lane];

  float m = -__builtin_inff();
#pragma unroll
  for (int c = 0; c < 8; ++c)
    m = fmaxf(m, fmaxf(fmaxf(v[c][0], v[c][1]), fmaxf(v[c][2], v[c][3])));
#pragma unroll
  for (int o = 32; o > 0; o >>= 1) m = fmaxf(m, __shfl_xor(m, o));

  float s = 0.f;
#pragma unroll
  for (int c = 0; c < 8; ++c) {
#pragma unroll
    for (int e = 0; e < 4; ++e) {
      v[c][e] = __expf(v[c][e] - m);
      s += v[c][e];
    }
  }
#pragma unroll
  for (int o = 32; o > 0; o >>= 1) s += __shfl_xor(s, o);
  const float inv = 1.0f / s;

  u16* prow = (u16*)srow;   // bf16 row at same base; valid elems 0..2047, stride 4096
#pragma unroll
  for (int c = 0; c < 8; ++c) {
    u16x4 o4 = { f2bf(v[c][0] * inv), f2bf(v[c][1] * inv),
                 f2bf(v[c][2] * inv), f2bf(v[c][3] * inv) };
    ((u16x4*)prow)[c * 64 + lane] = o4;
  }
}

// ---------- PV GEMM: out = P @ Vt^T ----------
// XCD-aware decode: region r = xcd (2x4 regions of 4x4 per batch),
// Vt stripes pinned per XCD.
__global__ __launch_bounds__(256, 2) void pv_kernel(
    const u16* __restrict__ P, const u16* __restrict__ vt, float* __restrict__ out)
{
  const int id   = blockIdx.x;          // 0..511
  const int xcd  = id & 7;
  const int s    = id >> 3;             // 0..63
  const int b    = s >> 4;              // batch 0..3
  const int slot = s & 15;
  const int bx   = (xcd & 1) * 4 + (slot & 3);   // H-tile 0..7
  const int by   = (xcd >> 1) * 4 + (slot >> 2); // Q-tile 0..15

  f32x16 acc[2][2];
  gemm_core_plain(P + ((size_t)b * S_LEN + by * 128) * (2 * S_LEN),
                  vt + ((size_t)b * HDIM + bx * 128) * S_LEN,
                  2 * S_LEN, S_LEN, S_LEN, acc);
  const int lane = threadIdx.x & 63, wave = threadIdx.x >> 6;
  const int wm = wave >> 1, wn = wave & 1;
#pragma unroll
  for (int i = 0; i < 2; ++i) {
#pragma unroll
    for (int j = 0; j < 2; ++j) {
#pragma unroll
      for (int r = 0; r < 16; ++r) {
        const int q = by * 128 + wm * 64 + i * 32 + ROW32(r, lane);
        const int h = bx * 128 + wn * 64 + j * 32 + (lane & 31);
        out[((size_t)b * S_LEN + q) * HDIM + h] = acc[i][j][r];
      }
    }
  }
}

extern "C" void kernel_launch(void* const* d_in, const int* in_sizes, int n_in,
                              void* d_out, int out_size, void* d_ws, size_t ws_size,
                              hipStream_t stream)
{
  const float* qkv  = (const float*)d_in[0];
  const void*  mask = d_in[1];
  const float* W    = (const float*)d_in[2];
  const float* bias = (const float*)d_in[3];
  float* out = (float*)d_out;
  char* ws = (char*)d_ws;

  const size_t off_mask = 0;
  const size_t off_Whi  = 32768;
  const size_t off_Wlo  = off_Whi + (size_t)N3H * DIN * 2;
  const size_t off_Qhi  = off_Wlo + (size_t)N3H * DIN * 2;
  const size_t off_Qlo  = off_Qhi + (size_t)NTOK * HDIM * 2;
  const size_t off_Khi  = off_Qlo + (size_t)NTOK * HDIM * 2;
  const size_t off_Klo  = off_Khi + (size_t)NTOK * HDIM * 2;
  const size_t off_Vt   = off_Klo + (size_t)NTOK * HDIM * 2;
  const size_t off_A    = off_Vt + (size_t)NTOK * HDIM * 2;
  const size_t off_Alo  = off_A + (size_t)NTOK * DIN * 2;
  const size_t off_sc   = off_A;  // scores (67MB) overlay A-split (dead after proj)
  // total ws requirement: off_A + BATCH*S*S*4 = ~156 MiB

  float* maskbias = (float*)(ws + off_mask);
  u16* Whi = (u16*)(ws + off_Whi);  u16* Wlo = (u16*)(ws + off_Wlo);
  u16* Qhi = (u16*)(ws + off_Qhi);  u16* Qlo = (u16*)(ws + off_Qlo);
  u16* Khi = (u16*)(ws + off_Khi);  u16* Klo = (u16*)(ws + off_Klo);
  u16* Vt  = (u16*)(ws + off_Vt);
  u16* Ahi = (u16*)(ws + off_A);    u16* Alo = (u16*)(ws + off_Alo);
  float* scores = (float*)(ws + off_sc);

  prep_mask_kernel<<<1, 256, 0, stream>>>((const unsigned char*)mask, maskbias);
  split_f32_kernel<<<NTOK * DIN / 1024, 256, 0, stream>>>(qkv, Ahi, Alo);
  splitWT_kernel<<<dim3(N3H / 32, DIN / 32), 256, 0, stream>>>(W, Whi, Wlo);
  proj_qk256_kernel<<<dim3(2 * HDIM / 256, NTOK / 256), 512, 0, stream>>>(
      Ahi, Alo, Whi, Wlo, bias, Qhi, Qlo, Khi, Klo);
  proj_v_kernel<<<dim3(HDIM / 128, NTOK / 128, 1), 256, 0, stream>>>(
      Ahi, Whi, bias, Vt);
  scores256_kernel<<<64 * BATCH, 512, 0, stream>>>(
      Qhi, Qlo, Khi, Klo, maskbias, scores);
  softmax_kernel<<<NTOK / 4, 256, 0, stream>>>(scores);
  pv_kernel<<<8 * 16 * BATCH, 256, 0, stream>>>(
      (const u16*)scores, Vt, out);
}